// Round 13
// baseline (56.845 us; speedup 1.0000x reference)
//
#include <hip/hip_runtime.h>
#include <cfloat>

// Problem constants (from reference): B=8, C=2, H=256, W=256
#define BB 8
#define CC 2
#define HH 256
#define WW 256

typedef unsigned long long ull;

static constexpr float  EDT_INF = 1e4f;          // matches reference INF
static constexpr int    NPIX    = BB * HH * WW;  // 524288
static constexpr double FXS     = 16777216.0;    // 2^24 fixed-point scale
#define NCOL  (BB * WW)                          // 2048 worker blocks
#define NLINE 64                                 // atomic spread width

// ---------------------------------------------------------------------------
// Distance^2 to nearest SET bit of zm (the zeros of the selected field),
// reproducing the reference f32 scan exactly (sentinels 1e4+pos+1 /
// 1e4+256-pos, g = fminf(fwd,bwd), return g*g).
__device__ __forceinline__ float hdist2(const ull* zm, int pos) {
    float fwd = EDT_INF + (float)(pos + 1);
    {
        int k = pos - 1;
        if (k >= 0) {
            int w = k >> 6;
            ull t = zm[w] & (~0ULL >> (63 - (k & 63)));
            for (;;) {
                if (t) { int j = (w << 6) + 63 - __builtin_clzll(t); fwd = (float)(pos - j); break; }
                if (--w < 0) break;
                t = zm[w];
            }
        }
    }
    float bwd = EDT_INF + (float)(256 - pos);
    {
        int k = pos + 1;
        if (k < 256) {
            int w = k >> 6;
            ull t = zm[w] & (~0ULL << (k & 63));
            for (;;) {
                if (t) { int j = (w << 6) + __builtin_ctzll(t); bwd = (float)(j - pos); break; }
                if (++w >= 4) break;
                t = zm[w];
            }
        }
    }
    float g = fminf(fwd, bwd);
    return g * g;
}

// Nearest SET bit distance (int), large sentinel when none.
__device__ __forceinline__ int nearest_set(const ull* zm, int pos) {
    int best = 1 << 20;
    {
        int k = pos - 1;
        if (k >= 0) {
            int w = k >> 6;
            ull t = zm[w] & (~0ULL >> (63 - (k & 63)));
            for (;;) {
                if (t) { int j = (w << 6) + 63 - __builtin_clzll(t); best = pos - j; break; }
                if (--w < 0) break;
                t = zm[w];
            }
        }
    }
    {
        int k = pos + 1;
        if (k < 256) {
            int w = k >> 6;
            ull t = zm[w] & (~0ULL << (k & 63));
            for (;;) {
                if (t) { int j = (w << 6) + __builtin_ctzll(t); best = min(best, j - pos); break; }
                if (++w >= 4) break;
                t = zm[w];
            }
        }
    }
    return best;
}

// ---------------------------------------------------------------------------
// K1: build ROW masks (coalesced: lanes across w) + per-block tmin partials.
// Block 0 also resets the reduction scratch for this call (runs before
// k_fused in stream order; kernel-end writeback makes it visible).
__global__ void k_masks(const float* __restrict__ preds,
                        const int*   __restrict__ target,
                        ull* __restrict__ mPC, ull* __restrict__ mGT0,
                        ull* __restrict__ mG255, int* __restrict__ tminPart,
                        ull* __restrict__ acc64, unsigned int* __restrict__ cnt,
                        ull* __restrict__ gAcc, unsigned int* __restrict__ gCnt) {
    const int blk = blockIdx.x;
    const int b  = blk >> 5;               // image
    const int ig = blk & 31;               // 8-row group
    const int wv = threadIdx.x >> 6;       // word index 0..3
    const int ln = threadIdx.x & 63;
    const int w  = (wv << 6) | ln;

    if (blk == 0) {
        if (threadIdx.x < NLINE) { acc64[threadIdx.x] = 0ULL; cnt[threadIdx.x] = 0u; }
        if (threadIdx.x == NLINE) { *gAcc = 0ULL; *gCnt = 0u; }
    }

    int tmin = 0x7fffffff;
#pragma unroll
    for (int r = 0; r < 8; ++r) {
        int i = ig * 8 + r;
        float a0 = preds[((size_t)b * CC + 0) * HH * WW + (size_t)i * WW + w];
        float a1 = preds[((size_t)b * CC + 1) * HH * WW + (size_t)i * WW + w];
        bool pc = (a1 > a0);               // argmax over C=2, ties -> class 0
        int tv = target[((size_t)b * HH + i) * WW + w];
        tmin = min(tmin, tv);
        ull bp = __ballot(pc);
        ull b0 = __ballot(tv > 0);
        ull b2 = __ballot(tv == 255);
        if (ln == 0) {
            size_t midx = ((size_t)b * HH + i) * 4 + wv;
            mPC[midx] = bp; mGT0[midx] = b0; mG255[midx] = b2;
        }
    }
    for (int off = 32; off > 0; off >>= 1) tmin = min(tmin, __shfl_down(tmin, off));
    __shared__ int swv[4];
    if (ln == 0) swv[wv] = tmin;
    __syncthreads();
    if (threadIdx.x == 0)
        tminPart[blk] = min(min(swv[0], swv[1]), min(swv[2], swv[3]));
}

// ---------------------------------------------------------------------------
// Per-column fused EDT + final math -> block-wide partial sum for column
// (b,j). i = threadIdx.x = row. Uses caller-provided LDS buffers.
__device__ __forceinline__ float column_partial(
        const int* __restrict__ target, int b, int j, int i, int tmin,
        const ull wp[4], const ull wg[4],
        float* s_p, float* s_g, ull* cshP, ull* cshG, float* sws) {
    const int wv = i >> 6, ln = i & 63;
    const bool pc = (wp[j >> 6] >> (j & 63)) & 1ULL;
    const bool gt = (wg[j >> 6] >> (j & 63)) & 1ULL;

    // own-polarity zero-masks
    ull zp[4], zg[4];
#pragma unroll
    for (int k = 0; k < 4; ++k) {
        zp[k] = pc ? ~wp[k] : wp[k];
        zg[k] = gt ? ~wg[k] : wg[k];
    }
    s_p[i] = hdist2(zp, j);
    s_g[i] = hdist2(zg, j);
    {
        ull bp = __ballot(pc);
        ull bg = __ballot(gt);
        if (ln == 0) { cshP[wv] = bp; cshG[wv] = bg; }
    }
    __syncthreads();

    // column opposite-polarity masks
    ull cp[4], cgm[4];
#pragma unroll
    for (int k = 0; k < 4; ++k) {
        ull P = cshP[k], G = cshG[k];
        cp[k]  = pc ? ~P : P;
        cgm[k] = gt ? ~G : G;
    }
    const int dvp = nearest_set(cp, i);
    const int dvg = nearest_set(cgm, i);

    // pc vertical search, pruned (opposite rows give exactly d^2 candidates)
    float mn = s_p[i];
    {
        int dmax = min(dvp, HH);
        for (int d = 1; d < dmax; ++d) {
            float dd = (float)(d * d);
            if (dd >= mn) break;
            int kl = i - d, kr = i + d;
            if (kl >= 0) mn = fminf(mn, dd + s_p[kl]);
            if (kr < HH) mn = fminf(mn, dd + s_p[kr]);
        }
        float dv = (float)dvp;
        mn = fminf(mn, dv * dv);
    }
    float pd = sqrtf(mn);

    // gt vertical search, pruned
    float mg = s_g[i];
    {
        int dmax = min(dvg, HH);
        for (int d = 1; d < dmax; ++d) {
            float dd = (float)(d * d);
            if (dd >= mg) break;
            int kl = i - d, kr = i + d;
            if (kl >= 0) mg = fminf(mg, dd + s_g[kl]);
            if (kr < HH) mg = fminf(mg, dd + s_g[kr]);
        }
        float dv = (float)dvg;
        mg = fminf(mg, dv * dv);
    }
    float gd = sqrtf(mg);

    // final elementwise math (reference op order)
    int tv = target[((size_t)b * HH + i) * WW + j];
    if (tv == 255) tv = tmin;
    float gtv = (float)tv;
    float pcv = pc ? 1.0f : 0.0f;
    float err  = fabsf(gtv - pcv);
    float dist = sqrtf(pd * pd + gd * gd);
    float mult = sqrtf(err * dist + 1e-9f);

    // deterministic block sum: wave shfl-add + fixed-order 4-term merge
    for (int off = 32; off > 0; off >>= 1) mult += __shfl_down(mult, off);
    if (ln == 0) sws[wv] = mult;
    __syncthreads();
    return ((sws[0] + sws[1]) + sws[2]) + sws[3];
}

// ---------------------------------------------------------------------------
// K2: 2048 worker blocks (R8 structure: 1 column each, full parallelism).
// Tail: hierarchical fixed-point atomic reduction — 64 spread lines
// (32 ops/line, parallel lines; memory-side atomics, no fences, no plain
// cross-block loads), line leaders -> 1 global acc (64 ops). Integer adds
// are associative -> deterministic output. Avoids R4 (same-line pile-up),
// R10 (grid.sync), R11 (col serialization), R12 (stale-L2 polling).
__global__ void __launch_bounds__(256)
k_fused(const int* __restrict__ target,
        const ull* __restrict__ mPC,
        const ull* __restrict__ mGT0,
        const ull* __restrict__ mG255,
        const int* __restrict__ tminPart,
        ull* __restrict__ acc64, unsigned int* __restrict__ cnt,
        ull* __restrict__ gAcc, unsigned int* __restrict__ gCnt,
        float* __restrict__ out) {
    const int blk = blockIdx.x;            // b*256 + j
    const int b = blk >> 8, j = blk & 255;
    const int i = threadIdx.x;             // row
    const int wv = i >> 6, ln = i & 63;

    __shared__ float s_p[HH], s_g[HH];
    __shared__ ull   cshP[4], cshG[4];
    __shared__ int   stw[4];
    __shared__ float sws[4];

    // tmin = min of the 256 k_masks partials
    {
        int v = tminPart[i];
        for (int off = 32; off > 0; off >>= 1) v = min(v, __shfl_down(v, off));
        if (ln == 0) stw[wv] = v;
    }
    __syncthreads();
    const int tmin = min(min(stw[0], stw[1]), min(stw[2], stw[3]));
    const bool allpos = (tmin > 0);

    // row i's masks: 4 consecutive ULLs each -> coalesced loads
    ull wp[4], wg[4];
    {
        const ull* pP = mPC   + ((size_t)b * HH + i) * 4;
        const ull* p0 = mGT0  + ((size_t)b * HH + i) * 4;
        const ull* p2 = mG255 + ((size_t)b * HH + i) * 4;
#pragma unroll
        for (int k = 0; k < 4; ++k) {
            wp[k] = pP[k];
            ull g = p0[k];
            if (!allpos) g &= ~p2[k];      // 255 -> tmin==0 -> not >0
            wg[k] = g;
        }
    }

    float psum = column_partial(target, b, j, i, tmin, wp, wg,
                                s_p, s_g, cshP, cshG, sws);

    if (i == 0) {
        ull q = (ull)llrint((double)psum * FXS);
        const int line = blk & (NLINE - 1);
        __hip_atomic_fetch_add(&acc64[line], q, __ATOMIC_RELAXED,
                               __HIP_MEMORY_SCOPE_AGENT);
        // release: line-acc add completes before the count bump
        unsigned int c = __hip_atomic_fetch_add(&cnt[line], 1u,
                                                __ATOMIC_ACQ_REL,
                                                __HIP_MEMORY_SCOPE_AGENT);
        if (c == (NCOL / NLINE) - 1) {     // line leader (last of 32)
            ull lineSum = __hip_atomic_fetch_add(&acc64[line], 0ULL,
                                                 __ATOMIC_RELAXED,
                                                 __HIP_MEMORY_SCOPE_AGENT);
            __hip_atomic_fetch_add(gAcc, lineSum, __ATOMIC_RELAXED,
                                   __HIP_MEMORY_SCOPE_AGENT);
            unsigned int g = __hip_atomic_fetch_add(gCnt, 1u,
                                                    __ATOMIC_ACQ_REL,
                                                    __HIP_MEMORY_SCOPE_AGENT);
            if (g == NLINE - 1) {          // final leader (last of 64)
                ull tot = __hip_atomic_fetch_add(gAcc, 0ULL, __ATOMIC_RELAXED,
                                                 __HIP_MEMORY_SCOPE_AGENT);
                out[0] = (float)((double)tot * (1.0 / FXS)
                                 * (1.0 / (double)NPIX));
            }
        }
    }
}

// ---------------------------------------------------------------------------
extern "C" void kernel_launch(void* const* d_in, const int* in_sizes, int n_in,
                              void* d_out, int out_size, void* d_ws, size_t ws_size,
                              hipStream_t stream) {
    const float* preds  = (const float*)d_in[0];
    const int*   target = (const int*)d_in[1];
    float* out = (float*)d_out;

    // ws layout: 3 mask arrays, tmin partials (256), reduction scratch
    ull* mPC   = (ull*)d_ws;                         // 8*256*4 ULL
    ull* mGT0  = mPC  + (size_t)BB * HH * 4;
    ull* mG255 = mGT0 + (size_t)BB * HH * 4;
    int* tminPart = (int*)(mG255 + (size_t)BB * HH * 4);       // 256 ints
    ull* acc64 = (ull*)(tminPart + 256);                       // 64 ULL
    ull* gAcc  = acc64 + NLINE;                                // 1 ULL
    unsigned int* cnt  = (unsigned int*)(gAcc + 1);            // 64 uints
    unsigned int* gCnt = cnt + NLINE;                          // 1 uint

    k_masks<<<256, 256, 0, stream>>>(preds, target, mPC, mGT0, mG255,
                                     tminPart, acc64, cnt, gAcc, gCnt);
    k_fused<<<NCOL, 256, 0, stream>>>(target, mPC, mGT0, mG255, tminPart,
                                      acc64, cnt, gAcc, gCnt, out);
}

// Round 14
// 26.011 us; speedup vs baseline: 2.1854x; 2.1854x over previous
//
#include <hip/hip_runtime.h>
#include <cfloat>

// Problem constants (from reference): B=8, C=2, H=256, W=256
#define BB 8
#define CC 2
#define HH 256
#define WW 256

typedef unsigned long long ull;

static constexpr float EDT_INF = 1e4f;          // matches reference INF
static constexpr int   NPIX    = BB * HH * WW;  // 524288

// ---------------------------------------------------------------------------
// 1D nearest-zero-bit distance^2 from a 256-bit mask, reproducing the
// reference f32 scan exactly: fwd d = m ? carry+1 : 0 (carry init 1e4),
// bwd symmetric, g = min(fwd,bwd), return g*g. pos = bit index.
__device__ __forceinline__ float g2_of(const ull* m, int pos, bool set) {
    if (!set) return 0.0f;
    float fwd = EDT_INF + (float)(pos + 1);   // run reaches low edge
    {
        int k = pos - 1;
        if (k >= 0) {
            int w = k >> 6;
            ull t = ~m[w] & (~0ULL >> (63 - (k & 63)));
            for (;;) {
                if (t) { int j = (w << 6) + 63 - __builtin_clzll(t); fwd = (float)(pos - j); break; }
                if (--w < 0) break;
                t = ~m[w];
            }
        }
    }
    float bwd = EDT_INF + (float)(256 - pos); // run reaches high edge
    {
        int k = pos + 1;
        if (k < 256) {
            int w = k >> 6;
            ull t = ~m[w] & (~0ULL << (k & 63));
            for (;;) {
                if (t) { int j = (w << 6) + __builtin_ctzll(t); bwd = (float)(j - pos); break; }
                if (++w >= 4) break;
                t = ~m[w];
            }
        }
    }
    float g = fminf(fwd, bwd);
    return g * g;
}

// ---------------------------------------------------------------------------
// K1: build ROW masks (coalesced: lanes across w) + per-block tmin partials.
// Grid: 256 blocks = b(8) x 8-row-group(32); 256 threads = 4 waves, wave wv
// covers w in [64*wv, 64*wv+64). Masks stored as mask[(b*256+i)*4 + wv].
// Three masks: pc (argmax preds), gt0 (tv>0), g255 (tv==255); the actual gt
// mask is fixed up in k_fused once tmin is known.
__global__ void k_masks(const float* __restrict__ preds,
                        const int*   __restrict__ target,
                        ull* __restrict__ mPC, ull* __restrict__ mGT0,
                        ull* __restrict__ mG255, int* __restrict__ tminPart) {
    const int blk = blockIdx.x;
    const int b  = blk >> 5;               // image
    const int ig = blk & 31;               // 8-row group
    const int wv = threadIdx.x >> 6;       // word index 0..3
    const int ln = threadIdx.x & 63;
    const int w  = (wv << 6) | ln;

    int tmin = 0x7fffffff;
#pragma unroll
    for (int r = 0; r < 8; ++r) {
        int i = ig * 8 + r;
        float a0 = preds[((size_t)b * CC + 0) * HH * WW + (size_t)i * WW + w];
        float a1 = preds[((size_t)b * CC + 1) * HH * WW + (size_t)i * WW + w];
        bool pc = (a1 > a0);               // argmax over C=2, ties -> class 0
        int tv = target[((size_t)b * HH + i) * WW + w];
        tmin = min(tmin, tv);
        ull bp = __ballot(pc);
        ull b0 = __ballot(tv > 0);
        ull b2 = __ballot(tv == 255);
        if (ln == 0) {
            size_t midx = ((size_t)b * HH + i) * 4 + wv;
            mPC[midx] = bp; mGT0[midx] = b0; mG255[midx] = b2;
        }
    }
    __shared__ int s[256];
    s[threadIdx.x] = tmin;
    __syncthreads();
    for (int st = 128; st > 0; st >>= 1) {
        if (threadIdx.x < st) s[threadIdx.x] = min(s[threadIdx.x], s[threadIdx.x + st]);
        __syncthreads();
    }
    if (threadIdx.x == 0) tminPart[blk] = s[0];
}

// ---------------------------------------------------------------------------
// K2: fused per-COLUMN kernel (axis-swapped separable EDT: horizontal 1D
// distance from row masks, then vertical min_k h2[k] + (i-k)^2 — exact EDT,
// identical values whenever the polarity has >=1 zero pixel in the image).
// One block per (b,j); thread i = row. No global atomics.
__global__ void k_fused(const int* __restrict__ target,
                        const ull* __restrict__ mPC,
                        const ull* __restrict__ mGT0,
                        const ull* __restrict__ mG255,
                        const int* __restrict__ tminPart,
                        float* __restrict__ partials) {
    const int blk = blockIdx.x;            // b*256 + j
    const int b = blk >> 8, j = blk & 255;
    const int i = threadIdx.x;             // row

    // tmin = min of the 256 block partials (one load per thread)
    __shared__ int stm[256];
    stm[i] = tminPart[i];
    __syncthreads();
    for (int st = 128; st > 0; st >>= 1) {
        if (i < st) stm[i] = min(stm[i], stm[i + st]);
        __syncthreads();
    }
    const int tmin = stm[0];
    const bool allpos = (tmin > 0);

    // row i's masks: 4 consecutive ULLs each -> coalesced dwordx4 loads
    ull wp[4], wg[4], np[4], ng[4];
    {
        const ull* pP = mPC   + ((size_t)b * HH + i) * 4;
        const ull* p0 = mGT0  + ((size_t)b * HH + i) * 4;
        const ull* p2 = mG255 + ((size_t)b * HH + i) * 4;
#pragma unroll
        for (int k = 0; k < 4; ++k) {
            wp[k] = pP[k];
            ull g = p0[k];
            if (!allpos) g &= ~p2[k];      // 255 -> tmin==0 -> not >0
            wg[k] = g;
            np[k] = ~wp[k]; ng[k] = ~wg[k];
        }
    }
    bool pc = (wp[j >> 6] >> (j & 63)) & 1ULL;
    bool gt = (wg[j >> 6] >> (j & 63)) & 1ULL;

    // stage the four horizontal distance^2 rows (value at (i,j) per polarity)
    __shared__ float s_pm[HH], s_pn[HH], s_gm[HH], s_gn[HH];
    s_pm[i] = g2_of(wp, j, pc);
    s_pn[i] = g2_of(np, j, !pc);
    s_gm[i] = g2_of(wg, j, gt);
    s_gn[i] = g2_of(ng, j, !gt);
    __syncthreads();

    // --- pc distance: vertical min with exact early exit ---
    const float* rv = pc ? s_pm : s_pn;
    float mn = rv[i];
    for (int d = 1; d < HH; ++d) {
        float dd = (float)(d * d);
        if (__all(dd >= mn)) break;
        int kl = i - d, kr = i + d;
        if (kl >= 0) mn = fminf(mn, dd + rv[kl]);
        if (kr < HH) mn = fminf(mn, dd + rv[kr]);
    }
    float pd = sqrtf(mn);

    // --- gt distance ---
    const float* rw = gt ? s_gm : s_gn;
    float mg = rw[i];
    for (int d = 1; d < HH; ++d) {
        float dd = (float)(d * d);
        if (__all(dd >= mg)) break;
        int kl = i - d, kr = i + d;
        if (kl >= 0) mg = fminf(mg, dd + rw[kl]);
        if (kr < HH) mg = fminf(mg, dd + rw[kr]);
    }
    float gd = sqrtf(mg);

    // --- final elementwise math (reference op order) ---
    int tv = target[((size_t)b * HH + i) * WW + j];   // uncoalesced, L2-fed
    if (tv == 255) tv = tmin;
    float gtv = (float)tv;
    float pcv = pc ? 1.0f : 0.0f;
    float err  = fabsf(gtv - pcv);
    float dist = sqrtf(pd * pd + gd * gd);
    float mult = sqrtf(err * dist + 1e-9f);

    __shared__ float red[HH];
    red[i] = mult;
    __syncthreads();
    for (int st = 128; st > 0; st >>= 1) {
        if (i < st) red[i] += red[i + st];
        __syncthreads();
    }
    if (i == 0) partials[blk] = red[0];
}

// ---------------------------------------------------------------------------
// K3: final deterministic reduction of B*W partials -> mean (fixed order)
__global__ void k_final(const float* __restrict__ partials, float* __restrict__ out) {
    __shared__ float s[256];
    float acc = 0.0f;
    for (int k = threadIdx.x; k < BB * WW; k += 256) acc += partials[k];
    s[threadIdx.x] = acc;
    __syncthreads();
    for (int st = 128; st > 0; st >>= 1) {
        if (threadIdx.x < st) s[threadIdx.x] += s[threadIdx.x + st];
        __syncthreads();
    }
    if (threadIdx.x == 0) out[0] = s[0] * (1.0f / (float)NPIX);  // /2^19: exact
}

// ---------------------------------------------------------------------------
extern "C" void kernel_launch(void* const* d_in, const int* in_sizes, int n_in,
                              void* d_out, int out_size, void* d_ws, size_t ws_size,
                              hipStream_t stream) {
    const float* preds  = (const float*)d_in[0];
    const int*   target = (const int*)d_in[1];
    float* out = (float*)d_out;

    // ws layout: 3 mask arrays (64 KB each), partials, tmin partials
    ull* mPC   = (ull*)d_ws;                         // 8*256*4 ULL
    ull* mGT0  = mPC  + (size_t)BB * HH * 4;
    ull* mG255 = mGT0 + (size_t)BB * HH * 4;
    float* partials = (float*)(mG255 + (size_t)BB * HH * 4);   // B*W floats
    int*   tminPart = (int*)(partials + BB * WW);              // 256 ints

    k_masks<<<256, 256, 0, stream>>>(preds, target, mPC, mGT0, mG255, tminPart);
    k_fused<<<BB * WW, HH, 0, stream>>>(target, mPC, mGT0, mG255, tminPart, partials);
    k_final<<<1, 256, 0, stream>>>(partials, out);
}